// Round 4
// baseline (3237.654 us; speedup 1.0000x reference)
//
#include <hip/hip_runtime.h>
#include <hip/hip_cooperative_groups.h>
#include <math.h>

namespace cg = cooperative_groups;

// ---------------- problem constants (fixed inputs: key 0) ----------------
#define BN 16384
#define DN 1024
#define CHEB_D 10  // Chebyshev degree per stage IN M (== degree 20 in C)

// ---------------- workspace layout (bytes, all 256-aligned) ----------------
static constexpr size_t OFF_C    = 0x000000;  // f32 [1024*1024]  G -> C -> Chat   [ZERO]
static constexpr size_t OFF_P    = 0x400000;  // f32 [16][64][1024] mv partials
static constexpr size_t OFF_Y0   = 0x800000;  // f32 [64][1024]
static constexpr size_t OFF_Y1   = 0x840000;
static constexpr size_t OFF_Y2   = 0x880000;
static constexpr size_t OFF_Y3   = 0x8C0000;
static constexpr size_t OFF_CQ   = 0x900000;  // f32 [64][1024]
static constexpr size_t OFF_S64  = 0x940000;  // f64 [64*64] gram
static constexpr size_t OFF_LF   = 0x948000;  // f32 [64*64] chol factor (recip diag)
static constexpr size_t OFF_T64  = 0x950000;  // f64 [64*64] RR matrix (in M-space)
static constexpr size_t OFF_V16  = 0x958000;  // f32 [64*16] top-16 eigvecs
static constexpr size_t OFF_UT   = 0x960000;  // f32 [16][1024]
static constexpr size_t OFF_UTT  = 0x970000;  // f32 [1024][16]
static constexpr size_t OFF_S16  = 0x980000;  // f32 [16]
static constexpr size_t OFF_CS   = 0x980100;  // f32 [1024] colsum           [ZERO]
static constexpr size_t OFF_TR   = 0x981100;  // f32 [1] trace               [ZERO]
static constexpr size_t OFF_SCAL = 0x981200;  // f32 [2] mid, inv_e
static constexpr size_t OFF_STAT = 0x981300;  // f32 [10*153] stats          [ZERO]
static constexpr size_t OFF_F    = 0x990000;  // f32 [16384*16] features
static constexpr size_t OFF_M    = 0xA90000;  // f32 [1024*1024] M = 2*Chat^2 - I [ZERO]
// end 0xE90000 (~15.6 MB of ws used)

// ---------------- standalone kernels ----------------

__global__ __launch_bounds__(256) void colsum_k(const float* __restrict__ X, float* __restrict__ cs){
  int b = blockIdx.x, t = threadIdx.x;
  float a0=0.f,a1=0.f,a2=0.f,a3=0.f;
  for (int r=0; r<256; ++r){
    const float4 v = *(const float4*)(X + (size_t)(b*256 + r)*1024 + t*4);
    a0 += v.x; a1 += v.y; a2 += v.z; a3 += v.w;
  }
  atomicAdd(&cs[t*4+0], a0); atomicAdd(&cs[t*4+1], a1);
  atomicAdd(&cs[t*4+2], a2); atomicAdd(&cs[t*4+3], a3);
}

// shared SYRK body: upper 128x128 tiles of A^T A, conflict-free fragment layout.
// fragment rows: {tx*4+i} and {64+tx*4+i} -> LDS reads at tx*4 / 64+tx*4 (2-way, free)
template<int KSPLIT, int KCHUNK>
__device__ __forceinline__ void syrk_body(const float* __restrict__ X, float* __restrict__ G, int KMAX){
  int bx = blockIdx.x;
  int tp = bx % 36, ks = bx / 36;
  int ti = 0, rem = tp;
  while (rem >= 8 - ti){ rem -= 8 - ti; ++ti; }
  int tj = ti + rem;                      // ti <= tj
  int k0 = ks * KCHUNK;
  int kend = k0 + KCHUNK; if (kend > KMAX) kend = KMAX;
  __shared__ __attribute__((aligned(16))) float Xa[16][132];
  __shared__ __attribute__((aligned(16))) float Xb[16][132];
  int t = threadIdx.x;
  int tx = t & 15, ty = t >> 4;
  int kk0 = t >> 5, f4 = t & 31;
  const float* ba = X + (size_t)kk0*1024 + ti*128 + f4*4;
  const float* bb = X + (size_t)kk0*1024 + tj*128 + f4*4;
  float4 pa0, pa1, pb0, pb1;
  {
    size_t o = (size_t)k0*1024;
    pa0 = *(const float4*)(ba + o);
    pb0 = *(const float4*)(bb + o);
    pa1 = *(const float4*)(ba + o + 8*1024);
    pb1 = *(const float4*)(bb + o + 8*1024);
  }
  float acc[8][8];
  #pragma unroll
  for (int i=0;i<8;++i)
    #pragma unroll
    for (int j=0;j<8;++j) acc[i][j] = 0.f;
  for (int kc = k0; kc < kend; kc += 16){
    __syncthreads();
    *(float4*)&Xa[kk0][f4*4]   = pa0;
    *(float4*)&Xa[kk0+8][f4*4] = pa1;
    *(float4*)&Xb[kk0][f4*4]   = pb0;
    *(float4*)&Xb[kk0+8][f4*4] = pb1;
    __syncthreads();
    if (kc + 16 < kend){
      size_t o = (size_t)(kc+16)*1024;
      pa0 = *(const float4*)(ba + o);
      pb0 = *(const float4*)(bb + o);
      pa1 = *(const float4*)(ba + o + 8*1024);
      pb1 = *(const float4*)(bb + o + 8*1024);
    }
    #pragma unroll
    for (int kk=0; kk<16; ++kk){
      float a[8], b[8];
      *(float4*)&a[0] = *(const float4*)&Xa[kk][tx*4];
      *(float4*)&a[4] = *(const float4*)&Xa[kk][64 + tx*4];
      *(float4*)&b[0] = *(const float4*)&Xb[kk][ty*4];
      *(float4*)&b[4] = *(const float4*)&Xb[kk][64 + ty*4];
      #pragma unroll
      for (int i=0;i<8;++i)
        #pragma unroll
        for (int j=0;j<8;++j) acc[i][j] += a[i]*b[j];
    }
  }
  #pragma unroll
  for (int i=0;i<8;++i){
    int ri = ti*128 + ((i<4) ? (tx*4+i) : (64 + tx*4 + (i-4)));
    #pragma unroll
    for (int j=0;j<8;++j){
      int cj = tj*128 + ((j<4) ? (ty*4+j) : (64 + ty*4 + (j-4)));
      atomicAdd(&G[(size_t)ri*1024 + cj], acc[i][j]);
    }
  }
}

// G = X^T X : grid 36*24 = 864, chunk 688 (last clamps to 560)
__global__ __launch_bounds__(256, 3) void syrk_k(const float* __restrict__ X, float* __restrict__ G){
  syrk_body<24, 688>(X, G, 16384);
}
// Macc = Chat^2 : grid 36*8 = 288, chunk 128
__global__ __launch_bounds__(256, 3) void syrkM_k(const float* __restrict__ X, float* __restrict__ G){
  syrk_body<8, 128>(X, G, 1024);
}

__global__ __launch_bounds__(256) void formC_k(float* __restrict__ C, const float* __restrict__ cs, float* __restrict__ tr){
  int g = blockIdx.x*256 + threadIdx.x;
  int i = g >> 10, j = g & 1023;
  if (j < i) return;
  float v = C[g] - cs[i]*cs[j]*(1.0f/16384.0f);
  C[g] = v;
  C[j*1024 + i] = v;
  if (i == j) atomicAdd(tr, v);
}

__global__ void scal_k(const float* __restrict__ tr, float* __restrict__ scal){
  float trD = tr[0] * (1.0f/1024.0f);
  float c = 1.40f * trD, a = 0.25f * trD;
  scal[0] = 0.5f*(c + a);       // mid
  scal[1] = 2.0f/(c - a);       // 1/e
}

__global__ __launch_bounds__(256) void formChat_k(float* __restrict__ C, const float* __restrict__ scal){
  int g = blockIdx.x*256 + threadIdx.x;
  int i = g >> 10, j = g & 1023;
  float mid = scal[0], ie = scal[1];
  C[g] = ie*(C[g] - ((i==j) ? mid : 0.f));
}

__global__ __launch_bounds__(256) void formM_k(float* __restrict__ M){
  int g = blockIdx.x*256 + threadIdx.x;
  int i = g >> 10, j = g & 1023;
  if (j < i) return;
  float v = 2.f*M[g] - ((i==j) ? 1.f : 0.f);
  M[g] = v;
  M[j*1024 + i] = v;
}

// ---------------- cooperative-kernel phase bodies ----------------

struct SMemMv   { float At[64][68]; float Bt[64][68]; };
struct SMemGram { float Ai[1024]; double red[16][17]; };
union  SMemU    { SMemMv mv; SMemGram gr; };

__device__ __forceinline__ void rng_phase(int b, int t, float* __restrict__ Y){
  int idx = b*256 + t;   // 65536
  unsigned h = (unsigned)idx * 2654435761u;
  h ^= h >> 16; h *= 2246822519u; h ^= h >> 13; h *= 3266489917u; h ^= h >> 16;
  Y[idx] = (float)(h & 0xFFFFFFu) * (2.0f/16777216.0f) - 1.0f;
}

// partial[ks] = Yt * Cm for k-chunk ks. 256 blocks: nt = b&15, ks = b>>4.
__device__ __forceinline__ void mv_phase(SMemU* sm, int b, int t,
                                         const float* __restrict__ Yt, const float* __restrict__ Cm,
                                         float* __restrict__ P){
  int nt = b & 15, ks = b >> 4;
  int n0 = nt*64, k0 = ks*64;
  float (*At)[68] = sm->mv.At;
  float (*Bt)[68] = sm->mv.Bt;
  #pragma unroll
  for (int w=0; w<4; ++w){
    int job = t + 256*w;
    int m  = job >> 4, f4 = job & 15;
    float4 v = *(const float4*)(Yt + (size_t)m*1024 + k0 + f4*4);
    At[f4*4+0][m] = v.x; At[f4*4+1][m] = v.y; At[f4*4+2][m] = v.z; At[f4*4+3][m] = v.w;
    int kk = job >> 4, fn = job & 15;
    *(float4*)&Bt[kk][fn*4] = *(const float4*)(Cm + (size_t)(k0+kk)*1024 + n0 + fn*4);
  }
  __syncthreads();
  int tm = t & 15, tn = t >> 4;
  float acc[4][4];
  #pragma unroll
  for (int i=0;i<4;++i)
    #pragma unroll
    for (int j=0;j<4;++j) acc[i][j]=0.f;
  for (int kk=0; kk<64; ++kk){
    float4 a = *(const float4*)&At[kk][tm*4];
    float4 bv4 = *(const float4*)&Bt[kk][tn*4];
    float av[4] = {a.x,a.y,a.z,a.w};
    float bv[4] = {bv4.x,bv4.y,bv4.z,bv4.w};
    #pragma unroll
    for (int i=0;i<4;++i)
      #pragma unroll
      for (int j=0;j<4;++j) acc[i][j] += av[i]*bv[j];
  }
  #pragma unroll
  for (int i=0;i<4;++i){
    float4 o; o.x=acc[i][0]; o.y=acc[i][1]; o.z=acc[i][2]; o.w=acc[i][3];
    *(float4*)(P + (size_t)(ks*64 + tm*4 + i)*1024 + n0 + tn*4) = o;
  }
}

// combine 16 partials; blocks 0..63. mode 0: out = S. mode 1: out = 2S - Tk1.
__device__ __forceinline__ void combine_phase(int b, int t, const float* __restrict__ P,
                                              const float* __restrict__ Tk1, float* __restrict__ out, int mode){
  if (b >= 64) return;
  int idx = (b*256 + t)*4;
  float s0=0.f,s1=0.f,s2=0.f,s3=0.f;
  #pragma unroll
  for (int ks=0; ks<16; ++ks){
    const float4 p = *(const float4*)(P + (size_t)ks*65536 + idx);
    s0 += p.x; s1 += p.y; s2 += p.z; s3 += p.w;
  }
  float4 o;
  if (mode == 0){
    o.x=s0; o.y=s1; o.z=s2; o.w=s3;
  } else {
    const float4 t1 = *(const float4*)(Tk1 + idx);
    o.x = 2.f*s0 - t1.x; o.y = 2.f*s1 - t1.y;
    o.z = 2.f*s2 - t1.z; o.w = 2.f*s3 - t1.w;
  }
  *(float4*)(out+idx) = o;
}

// S[i][j] = sum_k A[i][k]*B[j][k] (fp64). 256 blocks: i = b>>2, jg = b&3.
__device__ __forceinline__ void gram_phase(SMemU* sm, int b, int t,
                                           const float* __restrict__ A, const float* __restrict__ Bm,
                                           double* __restrict__ S){
  int i = b >> 2, jg = b & 3;
  float* Ai = sm->gr.Ai;
  double (*red)[17] = sm->gr.red;
  ((float4*)Ai)[t] = ((const float4*)(A + (size_t)i*1024))[t];
  __syncthreads();
  int jl = t >> 4, kp = t & 15;
  const float* Br = Bm + (size_t)(jg*16 + jl)*1024 + kp*64;
  const float* Ar = Ai + kp*64;
  double acc = 0.0;
  #pragma unroll 8
  for (int kk=0; kk<64; ++kk) acc += (double)Br[kk] * (double)Ar[kk];
  red[jl][kp] = acc;
  __syncthreads();
  if (t < 16){
    double s = 0.0;
    #pragma unroll
    for (int p2=0; p2<16; ++p2) s += red[jl? jl:0][0]*0.0 + red[t][p2];  // keep simple sum
    S[i*64 + jg*16 + t] = s;
  }
  __syncthreads();
}

// Qt = L^{-1} Yt forward substitution; blocks 0..3, k = b*256+t.
__device__ __forceinline__ void applysolve_phase(int b, int t, const float* __restrict__ Yin,
                                                 const float* __restrict__ Lf, float* __restrict__ Qout){
  if (b >= 4) return;
  int k = b*256 + t;
  float z[64];
  #pragma unroll
  for (int c=0; c<64; ++c){
    float v = Yin[(size_t)c*1024 + k];
    #pragma unroll
    for (int j=0; j<c; ++j) v -= Lf[c*64+j]*z[j];
    z[c] = v * Lf[c*64+c];   // diag stores reciprocal
  }
  #pragma unroll
  for (int c=0; c<64; ++c) Qout[(size_t)c*1024 + k] = z[c];
}

// ---------------- cooperative kernels (grid = 256 x 256) ----------------

__global__ __launch_bounds__(256) void coopA_k(float* P, float* Y0, float* Y1, float* Y2, float* Y3,
                                               const float* Mm, double* S64){
  __shared__ SMemU sm;
  cg::grid_group g = cg::this_grid();
  int b = blockIdx.x, t = threadIdx.x;
  rng_phase(b, t, Y0);
  g.sync();
  float* bufs[3] = {Y1, Y2, Y3};
  const float* cur = Y0; const float* prev = Y0;
  for (int s=0; s<CHEB_D; ++s){
    mv_phase(&sm, b, t, cur, Mm, P); g.sync();
    float* dst = bufs[s % 3];
    combine_phase(b, t, P, prev, dst, (s==0)?0:1); g.sync();
    prev = cur; cur = dst;
  }
  gram_phase(&sm, b, t, cur, cur, S64);   // cur = Y1
}

__global__ __launch_bounds__(256) void coopB_k(float* P, const float* Yin, float* Q,
                                               float* z0, float* z1, float* z2,
                                               const float* LF, const float* Mm, double* S64){
  __shared__ SMemU sm;
  cg::grid_group g = cg::this_grid();
  int b = blockIdx.x, t = threadIdx.x;
  applysolve_phase(b, t, Yin, LF, Q);
  g.sync();
  float* bufs[3] = {z0, z1, z2};
  const float* cur = Q; const float* prev = Q;
  for (int s=0; s<CHEB_D; ++s){
    mv_phase(&sm, b, t, cur, Mm, P); g.sync();
    float* dst = bufs[s % 3];
    combine_phase(b, t, P, prev, dst, (s==0)?0:1); g.sync();
    prev = cur; cur = dst;
  }
  gram_phase(&sm, b, t, cur, cur, S64);   // cur = z0
}

__global__ __launch_bounds__(256) void coopC_k(const float* Yin, float* Q, const float* LF, double* S64){
  __shared__ SMemU sm;
  cg::grid_group g = cg::this_grid();
  int b = blockIdx.x, t = threadIdx.x;
  applysolve_phase(b, t, Yin, LF, Q);
  g.sync();
  gram_phase(&sm, b, t, Q, Q, S64);
}

__global__ __launch_bounds__(256) void coopD_k(float* P, const float* Yin, float* Q,
                                               const float* LF, const float* Mm,
                                               float* CQ, double* T64){
  __shared__ SMemU sm;
  cg::grid_group g = cg::this_grid();
  int b = blockIdx.x, t = threadIdx.x;
  applysolve_phase(b, t, Yin, LF, Q);
  g.sync();
  mv_phase(&sm, b, t, Q, Mm, P);
  g.sync();
  combine_phase(b, t, P, (const float*)0, CQ, 0);
  g.sync();
  gram_phase(&sm, b, t, Q, CQ, T64);
}

// ---------------- small dense-algebra kernels ----------------

__global__ __launch_bounds__(64) void chol_k(const double* __restrict__ S, float* __restrict__ Lf){
  __shared__ double L[64][65];
  int t = threadIdx.x;
  for (int e=t; e<4096; e+=64) L[e>>6][e&63] = S[e];
  __syncthreads();
  for (int k=0; k<64; ++k){
    double lkk = sqrt(fmax(L[k][k], 1e-280));
    double r = 1.0/lkk;
    if (t == k) L[k][k] = lkk;
    if (t > k)  L[t][k] *= r;
    __syncthreads();
    if (t > k){
      double lik = L[t][k];
      for (int j=k+1; j<=t; ++j) L[t][j] -= lik * L[j][k];
    }
    __syncthreads();
  }
  for (int e=t; e<4096; e+=64){
    int i = e >> 6, j = e & 63;
    Lf[e] = (j < i) ? (float)L[i][j] : ((j == i) ? (float)(1.0/L[i][i]) : 0.f);
  }
}

__device__ __forceinline__ double wsumd(double v){
  #pragma unroll
  for (int off=32; off; off>>=1) v += __shfl_xor(v, off, 64);
  return v;
}
__device__ __forceinline__ float wsumf(float v){
  #pragma unroll
  for (int off=32; off; off>>=1) v += __shfl_xor(v, off, 64);
  return v;
}
__device__ __forceinline__ double wmind(double v){
  #pragma unroll
  for (int off=32; off; off>>=1) v = fmin(v, __shfl_xor(v, off, 64));
  return v;
}
__device__ __forceinline__ double wmaxd(double v){
  #pragma unroll
  for (int off=32; off; off>>=1) v = fmax(v, __shfl_xor(v, off, 64));
  return v;
}

__global__ __launch_bounds__(64) void eig16_k(const double* __restrict__ Tin, float* __restrict__ V16){
  __shared__ double A[64][65];
  __shared__ double vbuf[64], qbuf[64];
  __shared__ double dd[64], ee[64], kap[64];
  __shared__ float dF[64], eF[64], e2F[64];
  __shared__ float lamF[16];
  __shared__ float IV[5][64][16];
  __shared__ float W[16][68];
  __shared__ float vb32[64];
  int t = threadIdx.x;               // single wave

  for (int e=t; e<4096; e+=64){
    int i = e >> 6, j = e & 63;
    A[i][j] = 0.5*(Tin[i*64+j] + Tin[j*64+i]);
  }
  __syncthreads();

  for (int k=0; k<62; ++k){
    double xi = (t > k) ? A[t][k] : 0.0;
    double sigma = wsumd(xi*xi);
    double x1 = A[k+1][k];
    if (sigma > 1e-200){
      double r = sqrt(sigma);
      double alpha = (x1 >= 0.0) ? -r : r;
      double kappa = sigma - alpha*x1;
      double vk = xi;
      if (t == k+1) vk = x1 - alpha;
      vbuf[t] = (t > k) ? vk : 0.0;
      if (t > k) A[t][k] = vk;
      if (t == 0){ ee[k] = alpha; kap[k] = kappa; }
      __syncthreads();
      int j0 = (k+1) & ~7;
      double p0=0.0,p1=0.0,p2=0.0,p3=0.0;
      for (int j=j0; j<64; j+=8){
        p0 += A[t][j+0]*vbuf[j+0]; p1 += A[t][j+1]*vbuf[j+1];
        p2 += A[t][j+2]*vbuf[j+2]; p3 += A[t][j+3]*vbuf[j+3];
        p0 += A[t][j+4]*vbuf[j+4]; p1 += A[t][j+5]*vbuf[j+5];
        p2 += A[t][j+6]*vbuf[j+6]; p3 += A[t][j+7]*vbuf[j+7];
      }
      double pi = (t > k) ? ((p0+p1)+(p2+p3))/kappa : 0.0;
      double vp = wsumd((t > k) ? vbuf[t]*pi : 0.0);
      double Kc = vp / (2.0*kappa);
      double qi = (t > k) ? (pi - Kc*vbuf[t]) : 0.0;
      qbuf[t] = qi;
      __syncthreads();
      double vi = (t > k) ? vbuf[t] : 0.0;
      for (int j=j0; j<64; j+=8){
        A[t][j+0] -= vi*qbuf[j+0] + qi*vbuf[j+0];
        A[t][j+1] -= vi*qbuf[j+1] + qi*vbuf[j+1];
        A[t][j+2] -= vi*qbuf[j+2] + qi*vbuf[j+2];
        A[t][j+3] -= vi*qbuf[j+3] + qi*vbuf[j+3];
        A[t][j+4] -= vi*qbuf[j+4] + qi*vbuf[j+4];
        A[t][j+5] -= vi*qbuf[j+5] + qi*vbuf[j+5];
        A[t][j+6] -= vi*qbuf[j+6] + qi*vbuf[j+6];
        A[t][j+7] -= vi*qbuf[j+7] + qi*vbuf[j+7];
      }
      __syncthreads();
    } else {
      if (t == 0){ ee[k] = 0.0; kap[k] = 0.0; }
      __syncthreads();
    }
  }
  dd[t] = A[t][t];
  if (t == 0){ ee[62] = A[63][62]; ee[63] = 0.0; kap[62] = 0.0; kap[63] = 0.0; }
  __syncthreads();
  dF[t] = (float)dd[t];
  eF[t] = (float)ee[t];
  e2F[t] = (float)(ee[t]*ee[t]);
  __syncthreads();

  double em1 = (t > 0) ? fabs(ee[t-1]) : 0.0;
  double ep  = fabs(ee[t]);
  double glo = wmind(dd[t] - em1 - ep);
  double ghi = wmaxd(dd[t] + em1 + ep);
  double span = ghi - glo + 1.0;
  float lo = (float)(glo - 0.001*span), hi = (float)(ghi + 0.001*span);

  int m = 48 + (t & 15);
  const float PIV = 1e-10f;
  for (int it=0; it<30; ++it){
    float x = 0.5f*(lo + hi);
    float q = dF[0] - x;
    int c = (q < 0.f) ? 1 : 0;
    #pragma unroll 1
    for (int j=1; j<64; ++j){
      float qs = (fabsf(q) < PIV) ? ((q < 0.f) ? -PIV : PIV) : q;
      q = dF[j] - x - e2F[j-1]/qs;
      c += (q < 0.f) ? 1 : 0;
    }
    if (c <= m) lo = x; else hi = x;
  }
  if (t < 16) lamF[t] = 0.5f*(lo + hi);
  __syncthreads();

  #define DLa(i) IV[0][i][t]
  #define DDa(i) IV[1][i][t]
  #define DUa(i) IV[2][i][t]
  #define DU2a(i) IV[3][i][t]
  #define Bv(i)  IV[4][i][t]
  if (t < 16){
    float lam = lamF[t];
    const float PIVF = 1e-6f;
    for (int i=0; i<64; ++i){
      DDa(i) = dF[i] - lam;
      DU2a(i) = 0.f;
      if (i < 63){ DUa(i) = eF[i]; DLa(i) = eF[i]; }
      unsigned hsh = (unsigned)(i*131 + t*1009 + 7);
      hsh ^= hsh >> 13; hsh *= 2654435761u; hsh ^= hsh >> 16;
      Bv(i) = (float)(hsh & 0xFFFF) * (1.5f/65536.0f) + 0.25f;
    }
    unsigned long long piv = 0ull;
    for (int i=0; i<63; ++i){
      float di = DDa(i), dli = DLa(i);
      if (fabsf(di) >= fabsf(dli)){
        if (fabsf(di) < PIVF) di = (di < 0.f) ? -PIVF : PIVF;
        float f = dli/di;
        DDa(i) = di; DLa(i) = f;
        DDa(i+1) -= f*DUa(i);
      } else {
        float f = di/dli;
        DDa(i) = dli; DLa(i) = f;
        float tmp = DUa(i);
        DUa(i) = DDa(i+1);
        DDa(i+1) = tmp - f*DDa(i+1);
        if (i < 62){ DU2a(i) = DUa(i+1); DUa(i+1) = -f*DUa(i+1); }
        piv |= (1ull << i);
      }
    }
    #pragma unroll 1
    for (int iter=0; iter<2; ++iter){
      for (int i=0; i<63; ++i){
        if (!((piv >> i) & 1ull)){
          Bv(i+1) -= DLa(i)*Bv(i);
        } else {
          float tm = Bv(i);
          Bv(i) = Bv(i+1);
          Bv(i+1) = tm - DLa(i)*Bv(i);
        }
      }
      float p63 = DDa(63); if (fabsf(p63) < PIVF) p63 = (p63 < 0.f) ? -PIVF : PIVF;
      Bv(63) = Bv(63)/p63;
      float p62 = DDa(62); if (fabsf(p62) < PIVF) p62 = (p62 < 0.f) ? -PIVF : PIVF;
      Bv(62) = (Bv(62) - DUa(62)*Bv(63))/p62;
      for (int i=61; i>=0; --i){
        float pi2 = DDa(i); if (fabsf(pi2) < PIVF) pi2 = (pi2 < 0.f) ? -PIVF : PIVF;
        Bv(i) = (Bv(i) - DUa(i)*Bv(i+1) - DU2a(i)*Bv(i+2))/pi2;
      }
      float ss = 0.f;
      for (int i=0; i<64; ++i){ float z = Bv(i); ss += z*z; }
      float rn = rsqrtf(fmaxf(ss, 1e-30f));
      for (int i=0; i<64; ++i) Bv(i) *= rn;
    }
    for (int i=0; i<64; ++i) W[t][i] = Bv(i);
  }
  __syncthreads();

  for (int c=0; c<16; ++c){
    float wi = W[c][t];
    float s2 = wsumf(wi*wi);
    float rn = rsqrtf(fmaxf(s2, 1e-30f));
    wi *= rn;
    W[c][t] = wi;
    for (int c2=c+1; c2<16; ++c2){
      float d2 = wsumf(wi * W[c2][t]);
      W[c2][t] -= d2*wi;
    }
    __syncthreads();
  }

  int cc = t >> 2, part = t & 3;
  for (int k=61; k>=0; --k){
    double kpd = kap[k];
    if (kpd == 0.0) continue;
    float invk = (float)(1.0/kpd);
    vb32[t] = (t > k) ? (float)A[t][k] : 0.f;
    __syncthreads();
    float ps = 0.f;
    #pragma unroll
    for (int mm=0; mm<16; ++mm){
      int i = part*16 + mm;
      ps += vb32[i]*W[cc][i];
    }
    ps += __shfl_xor(ps, 1, 64);
    ps += __shfl_xor(ps, 2, 64);
    float sc = ps * invk;
    #pragma unroll
    for (int mm=0; mm<16; ++mm){
      int i = part*16 + mm;
      W[cc][i] -= vb32[i]*sc;
    }
    __syncthreads();
  }

  for (int e=t; e<1024; e+=64){
    int j = e >> 4, c = e & 15;
    V16[e] = W[c][j];
  }
}
#undef DLa
#undef DDa
#undef DUa
#undef DU2a
#undef Bv

__global__ __launch_bounds__(256) void buildUt_k(const float* __restrict__ V16,
                                                 const float* __restrict__ Qt, float* __restrict__ Ut, float* __restrict__ UtT){
  int bx = blockIdx.x;
  int c = bx & 15, kc = bx >> 4;
  int k = kc*256 + threadIdx.x;
  float acc = 0.f;
  #pragma unroll
  for (int j=0; j<64; ++j) acc += V16[j*16 + c] * Qt[(size_t)j*1024 + k];
  Ut[(size_t)c*1024 + k] = acc;
  UtT[(size_t)k*16 + c] = acc;
}

__global__ void s16_k(const float* __restrict__ cs, const float* __restrict__ Ut, float* __restrict__ s16){
  __shared__ float red[16][17];
  int t = threadIdx.x;
  int c = t & 15, part = t >> 4;
  float acc = 0.f;
  for (int d=0; d<64; ++d) acc += cs[part*64 + d] * Ut[(size_t)c*1024 + part*64 + d];
  red[c][part] = acc;
  __syncthreads();
  if (t < 16){
    float s = 0.f;
    #pragma unroll
    for (int p2=0; p2<16; ++p2) s += red[t][p2];
    s16[t] = s * (1.0f/16384.0f);
  }
}

__global__ __launch_bounds__(256) void proj_k(const float* __restrict__ X, const float* __restrict__ UtT,
                                              const float* __restrict__ s16, float* __restrict__ F){
  int r0 = blockIdx.x * 64;
  int t = threadIdx.x;
  __shared__ __attribute__((aligned(16))) float uts[16384];   // [1024][16]
  #pragma unroll
  for (int w=0; w<16; ++w)
    ((float4*)uts)[t + 256*w] = ((const float4*)UtT)[t + 256*w];
  __syncthreads();
  int row = t & 63, kp = t >> 6;
  const float* xr = X + (size_t)(r0 + row)*1024 + kp*256;
  const float* ut = uts + kp*256*16;
  float acc[16];
  #pragma unroll
  for (int c=0;c<16;++c) acc[c] = 0.f;
  for (int dd=0; dd<256; dd+=4){
    float4 xv4 = *(const float4*)(xr + dd);
    float xv[4] = {xv4.x, xv4.y, xv4.z, xv4.w};
    #pragma unroll
    for (int u=0; u<4; ++u)
      #pragma unroll
      for (int c=0;c<16;++c) acc[c] += xv[u] * ut[(dd+u)*16 + c];
  }
  __shared__ float part[4][64][16];
  #pragma unroll
  for (int c=0;c<16;++c) part[kp][row][c] = acc[c];
  __syncthreads();
  int cq = t >> 6;
  #pragma unroll
  for (int ccx=0; ccx<4; ++ccx){
    int c = cq*4 + ccx;
    float v = part[0][row][c] + part[1][row][c] + part[2][row][c] + part[3][row][c] - s16[c];
    F[(size_t)(r0 + row)*16 + c] = v;
  }
}

__global__ __launch_bounds__(256) void stats_k(const float* __restrict__ F, const int* __restrict__ lbl, float* __restrict__ SG){
  __shared__ float st[10][154];
  int t = threadIdx.x;
  for (int e=t; e<1540; e+=256) st[e/154][e%154] = 0.f;
  __syncthreads();
  int r = blockIdx.x*256 + t;
  float f[16];
  #pragma unroll
  for (int w=0; w<4; ++w){
    float4 v = *(const float4*)(F + (size_t)r*16 + w*4);
    f[w*4+0]=v.x; f[w*4+1]=v.y; f[w*4+2]=v.z; f[w*4+3]=v.w;
  }
  int c = lbl[r];
  if ((unsigned)c < 10u){
    float* bs = &st[c][0];
    atomicAdd(&bs[0], 1.f);
    #pragma unroll
    for (int a=0;a<16;++a) atomicAdd(&bs[1+a], f[a]);
    int sidx = 17;
    #pragma unroll
    for (int a=0;a<16;++a)
      #pragma unroll
      for (int b2=a;b2<16;++b2) atomicAdd(&bs[sidx++], f[a]*f[b2]);
  }
  __syncthreads();
  for (int e=t; e<1530; e+=256) atomicAdd(&SG[e], st[e/153][e%153]);
}

__global__ __launch_bounds__(256) void final_k(const float* __restrict__ SG, float* __restrict__ out){
  __shared__ double cnt[10], safe[10], ldet[10];
  __shared__ double mean[10][16];
  __shared__ double Sig[10][16][16];
  __shared__ double Inv[10][16][16];
  __shared__ double red[128];
  int t = threadIdx.x;
  if (t < 10){
    double c0 = (double)SG[t*153];
    cnt[t] = c0; safe[t] = (c0 > 0.0) ? c0 : 1.0;
  }
  __syncthreads();
  for (int e=t; e<160; e+=256){
    int c = e >> 4, a = e & 15;
    mean[c][a] = (double)SG[c*153 + 1 + a] / safe[c];
  }
  __syncthreads();
  for (int e=t; e<2560; e+=256){
    int c = e >> 8, ab = e & 255, a = ab >> 4, b2 = ab & 15;
    int lo = a < b2 ? a : b2, hi = a < b2 ? b2 : a;
    int ti = lo*(33 - lo)/2 + (hi - lo);
    Sig[c][a][b2] = (double)SG[c*153 + 17 + ti]/safe[c] - mean[c][a]*mean[c][b2] + ((a==b2)?1.0:0.0);
  }
  __syncthreads();
  if (t < 10){
    for (int a=0;a<16;++a)
      for (int b2=0;b2<16;++b2) Inv[t][a][b2] = Sig[t][a][b2];
    double ld2 = 0.0;
    for (int k=0;k<16;++k){
      double v = Inv[t][k][k];
      for (int j=0;j<k;++j) v -= Inv[t][k][j]*Inv[t][k][j];
      v = fmax(v, 1e-280);
      double lkk = sqrt(v);
      Inv[t][k][k] = lkk; ld2 += log(lkk);
      for (int i=k+1;i<16;++i){
        double w = Inv[t][i][k];
        for (int j=0;j<k;++j) w -= Inv[t][i][j]*Inv[t][k][j];
        Inv[t][i][k] = w / lkk;
      }
    }
    ldet[t] = 2.0*ld2;
    for (int j=0;j<16;++j){
      double dj = 1.0 / Inv[t][j][j];
      Inv[t][j][j] = dj;
      for (int i=j+1;i<16;++i){
        double ssum = Inv[t][i][j]*dj;
        for (int k=j+1;k<i;++k) ssum += Inv[t][i][k]*Inv[t][k][j];
        Inv[t][i][j] = -ssum / Inv[t][i][i];
      }
    }
    double dg[16];
    #pragma unroll
    for (int a=0;a<16;++a){
      double s2 = 0.0;
      for (int k=a;k<16;++k){ double x = Inv[t][k][a]; s2 += x*x; }
      dg[a] = s2;
    }
    for (int a=0;a<16;++a)
      for (int b2=a+1;b2<16;++b2){
        double s2 = 0.0;
        for (int k=b2;k<16;++k) s2 += Inv[t][k][a]*Inv[t][k][b2];
        Inv[t][a][b2] = s2;
      }
    for (int a=0;a<16;++a) Inv[t][a][a] = dg[a];
    for (int a=0;a<16;++a)
      for (int b2=a+1;b2<16;++b2) Inv[t][b2][a] = Inv[t][a][b2];
  }
  __syncthreads();
  double contrib = 0.0;
  if (t < 100){
    int i = t/10, j = t%10;
    if (i != j && cnt[i] > 0.0 && cnt[j] > 0.0){
      double tr = 0.0;
      for (int a=0;a<16;++a)
        for (int b2=0;b2<16;++b2) tr += Inv[j][a][b2]*Sig[i][b2][a];
      double dm[16];
      #pragma unroll
      for (int a=0;a<16;++a) dm[a] = mean[j][a] - mean[i][a];
      double mah = 0.0;
      for (int a=0;a<16;++a){
        double rs = 0.0;
        for (int b2=0;b2<16;++b2) rs += Inv[j][a][b2]*dm[b2];
        mah += dm[a]*rs;
      }
      double kl = 0.5*(tr + mah - 16.0 + ldet[j] - ldet[i]);
      contrib = kl * cnt[i]*cnt[j];
    }
  }
  if (t < 128) red[t] = contrib;
  __syncthreads();
  for (int off=64; off>0; off >>= 1){
    if (t < off) red[t] += red[t+off];
    __syncthreads();
  }
  if (t == 0) out[0] = (float)(red[0] / (16384.0*16384.0*16384.0));
}

// ---------------- host ----------------
extern "C" void kernel_launch(void* const* d_in, const int* in_sizes, int n_in,
                              void* d_out, int out_size, void* d_ws, size_t ws_size,
                              hipStream_t stream){
  (void)in_sizes; (void)n_in; (void)out_size; (void)ws_size;
  const float* X  = (const float*)d_in[0];
  const int* lbl  = (const int*)d_in[1];
  char* ws = (char*)d_ws;
  float*  C    = (float*)(ws + OFF_C);
  float*  Mm   = (float*)(ws + OFF_M);
  float*  P    = (float*)(ws + OFF_P);
  float*  Y0   = (float*)(ws + OFF_Y0);
  float*  Y1   = (float*)(ws + OFF_Y1);
  float*  Y2   = (float*)(ws + OFF_Y2);
  float*  Y3   = (float*)(ws + OFF_Y3);
  float*  CQ   = (float*)(ws + OFF_CQ);
  double* S64  = (double*)(ws + OFF_S64);
  float*  LF   = (float*)(ws + OFF_LF);
  double* T64  = (double*)(ws + OFF_T64);
  float*  V16  = (float*)(ws + OFF_V16);
  float*  UT   = (float*)(ws + OFF_UT);
  float*  UTT  = (float*)(ws + OFF_UTT);
  float*  S16  = (float*)(ws + OFF_S16);
  float*  CS   = (float*)(ws + OFF_CS);
  float*  TRC  = (float*)(ws + OFF_TR);
  float*  SCAL = (float*)(ws + OFF_SCAL);
  float*  STAT = (float*)(ws + OFF_STAT);
  float*  F    = (float*)(ws + OFF_F);
  float*  OUT  = (float*)d_out;

  hipMemsetAsync(C, 0, 4*1024*1024, stream);
  hipMemsetAsync(Mm, 0, 4*1024*1024, stream);
  hipMemsetAsync(ws + OFF_CS, 0, 12800, stream);   // CS + TR + SCAL + STAT

  colsum_k<<<64, 256, 0, stream>>>(X, CS);
  syrk_k<<<36*24, 256, 0, stream>>>(X, C);
  formC_k<<<4096, 256, 0, stream>>>(C, CS, TRC);
  scal_k<<<1, 1, 0, stream>>>(TRC, SCAL);
  formChat_k<<<4096, 256, 0, stream>>>(C, SCAL);
  syrkM_k<<<36*8, 256, 0, stream>>>(C, Mm);
  formM_k<<<4096, 256, 0, stream>>>(Mm);

  dim3 g256(256), b256(256);
  {
    void* args[] = {&P, &Y0, &Y1, &Y2, &Y3, (void*)&Mm, &S64};
    hipLaunchCooperativeKernel((const void*)coopA_k, g256, b256, args, 0, stream);
  }
  chol_k<<<1, 64, 0, stream>>>(S64, LF);
  {
    // apply(Y1->Y2), cheb from Y2 via {Y0,Y1,Y3} -> Y0, gram(Y0)
    void* args[] = {&P, (void*)&Y1, &Y2, &Y0, &Y1, &Y3, (void*)&LF, (void*)&Mm, &S64};
    hipLaunchCooperativeKernel((const void*)coopB_k, g256, b256, args, 0, stream);
  }
  chol_k<<<1, 64, 0, stream>>>(S64, LF);
  {
    // apply(Y0->Y1), gram(Y1)
    void* args[] = {(void*)&Y0, &Y1, (void*)&LF, &S64};
    hipLaunchCooperativeKernel((const void*)coopC_k, g256, b256, args, 0, stream);
  }
  chol_k<<<1, 64, 0, stream>>>(S64, LF);
  {
    // apply(Y1->Y2)=Qf, RR: mv, combine->CQ, gram(Y2,CQ)->T64
    void* args[] = {&P, (void*)&Y1, &Y2, (void*)&LF, (void*)&Mm, &CQ, &T64};
    hipLaunchCooperativeKernel((const void*)coopD_k, g256, b256, args, 0, stream);
  }
  eig16_k<<<1, 64, 0, stream>>>(T64, V16);
  buildUt_k<<<64, 256, 0, stream>>>(V16, Y2, UT, UTT);

  s16_k<<<1, 256, 0, stream>>>(CS, UT, S16);
  proj_k<<<256, 256, 0, stream>>>(X, UTT, S16, F);
  stats_k<<<64, 256, 0, stream>>>(F, lbl, STAT);
  final_k<<<1, 256, 0, stream>>>(STAT, OUT);
}

// Round 5
// 1757.458 us; speedup vs baseline: 1.8422x; 1.8422x over previous
//
#include <hip/hip_runtime.h>
#include <math.h>

// ---------------- problem constants (fixed inputs: key 0) ----------------
#define BN 16384
#define DN 1024
#define CHEB_D 10  // Chebyshev degree per stage IN M (== degree 20 in C)

// ---------------- workspace layout (bytes, all 256-aligned) ----------------
static constexpr size_t OFF_C    = 0x000000;  // f32 [1024*1024]  G -> C -> Chat   [ZERO]
static constexpr size_t OFF_P    = 0x400000;  // f32 [16][64][1024] mv partials
static constexpr size_t OFF_Y0   = 0x800000;  // f32 [64][1024]
static constexpr size_t OFF_Y1   = 0x840000;
static constexpr size_t OFF_Y2   = 0x880000;
static constexpr size_t OFF_Y3   = 0x8C0000;
static constexpr size_t OFF_CQ   = 0x900000;  // f32 [64][1024]
static constexpr size_t OFF_S64  = 0x940000;  // f64 [64*64] gram
static constexpr size_t OFF_LF   = 0x948000;  // f32 [64*64] chol factor (recip diag)
static constexpr size_t OFF_T64  = 0x950000;  // f64 [64*64] RR matrix (in M-space)
static constexpr size_t OFF_V16  = 0x958000;  // f32 [64*16] top-16 eigvecs
static constexpr size_t OFF_UT   = 0x960000;  // f32 [16][1024]
static constexpr size_t OFF_UTT  = 0x970000;  // f32 [1024][16]
static constexpr size_t OFF_S16  = 0x980000;  // f32 [16]
static constexpr size_t OFF_CS   = 0x980100;  // f32 [1024] colsum           [ZERO]
static constexpr size_t OFF_TR   = 0x981100;  // f32 [1] trace               [ZERO]
static constexpr size_t OFF_SCAL = 0x981200;  // f32 [2] mid, inv_e
static constexpr size_t OFF_STAT = 0x981300;  // f32 [10*153] stats          [ZERO]
static constexpr size_t OFF_F    = 0x990000;  // f32 [16384*16] features
static constexpr size_t OFF_M    = 0xA90000;  // f32 [1024*1024] M = 2*Chat^2 - I [ZERO]
// end 0xE90000 (~15.6 MB of ws used)

// ---------------- kernels ----------------

__global__ __launch_bounds__(256) void colsum_k(const float* __restrict__ X, float* __restrict__ cs){
  int b = blockIdx.x, t = threadIdx.x;
  float a0=0.f,a1=0.f,a2=0.f,a3=0.f;
  for (int r=0; r<256; ++r){
    const float4 v = *(const float4*)(X + (size_t)(b*256 + r)*1024 + t*4);
    a0 += v.x; a1 += v.y; a2 += v.z; a3 += v.w;
  }
  atomicAdd(&cs[t*4+0], a0); atomicAdd(&cs[t*4+1], a1);
  atomicAdd(&cs[t*4+2], a2); atomicAdd(&cs[t*4+3], a3);
}

// SYRK body: upper 128x128 tiles of A^T A, conflict-free fragment layout.
// fragment rows: {tx*4+i} and {64+tx*4+i} -> LDS reads at tx*4 / 64+tx*4 (2-way, free)
template<int KCHUNK>
__device__ __forceinline__ void syrk_body(const float* __restrict__ X, float* __restrict__ G, int KMAX){
  int bx = blockIdx.x;
  int tp = bx % 36, ks = bx / 36;
  int ti = 0, rem = tp;
  while (rem >= 8 - ti){ rem -= 8 - ti; ++ti; }
  int tj = ti + rem;                      // ti <= tj
  int k0 = ks * KCHUNK;
  int kend = k0 + KCHUNK; if (kend > KMAX) kend = KMAX;
  __shared__ __attribute__((aligned(16))) float Xa[16][132];
  __shared__ __attribute__((aligned(16))) float Xb[16][132];
  int t = threadIdx.x;
  int tx = t & 15, ty = t >> 4;
  int kk0 = t >> 5, f4 = t & 31;
  const float* ba = X + (size_t)kk0*1024 + ti*128 + f4*4;
  const float* bb = X + (size_t)kk0*1024 + tj*128 + f4*4;
  float4 pa0, pa1, pb0, pb1;
  {
    size_t o = (size_t)k0*1024;
    pa0 = *(const float4*)(ba + o);
    pb0 = *(const float4*)(bb + o);
    pa1 = *(const float4*)(ba + o + 8*1024);
    pb1 = *(const float4*)(bb + o + 8*1024);
  }
  float acc[8][8];
  #pragma unroll
  for (int i=0;i<8;++i)
    #pragma unroll
    for (int j=0;j<8;++j) acc[i][j] = 0.f;
  for (int kc = k0; kc < kend; kc += 16){
    __syncthreads();
    *(float4*)&Xa[kk0][f4*4]   = pa0;
    *(float4*)&Xa[kk0+8][f4*4] = pa1;
    *(float4*)&Xb[kk0][f4*4]   = pb0;
    *(float4*)&Xb[kk0+8][f4*4] = pb1;
    __syncthreads();
    if (kc + 16 < kend){
      size_t o = (size_t)(kc+16)*1024;
      pa0 = *(const float4*)(ba + o);
      pb0 = *(const float4*)(bb + o);
      pa1 = *(const float4*)(ba + o + 8*1024);
      pb1 = *(const float4*)(bb + o + 8*1024);
    }
    #pragma unroll
    for (int kk=0; kk<16; ++kk){
      float a[8], b[8];
      *(float4*)&a[0] = *(const float4*)&Xa[kk][tx*4];
      *(float4*)&a[4] = *(const float4*)&Xa[kk][64 + tx*4];
      *(float4*)&b[0] = *(const float4*)&Xb[kk][ty*4];
      *(float4*)&b[4] = *(const float4*)&Xb[kk][64 + ty*4];
      #pragma unroll
      for (int i=0;i<8;++i)
        #pragma unroll
        for (int j=0;j<8;++j) acc[i][j] += a[i]*b[j];
    }
  }
  #pragma unroll
  for (int i=0;i<8;++i){
    int ri = ti*128 + ((i<4) ? (tx*4+i) : (64 + tx*4 + (i-4)));
    #pragma unroll
    for (int j=0;j<8;++j){
      int cj = tj*128 + ((j<4) ? (ty*4+j) : (64 + ty*4 + (j-4)));
      atomicAdd(&G[(size_t)ri*1024 + cj], acc[i][j]);
    }
  }
}

// G = X^T X : grid 36*24 = 864, chunk 688 (last clamps to 560)
__global__ __launch_bounds__(256, 3) void syrk_k(const float* __restrict__ X, float* __restrict__ G){
  syrk_body<688>(X, G, 16384);
}
// Macc = Chat^2 : grid 36*8 = 288, chunk 128
__global__ __launch_bounds__(256, 3) void syrkM_k(const float* __restrict__ X, float* __restrict__ G){
  syrk_body<128>(X, G, 1024);
}

__global__ __launch_bounds__(256) void formC_k(float* __restrict__ C, const float* __restrict__ cs, float* __restrict__ tr){
  int g = blockIdx.x*256 + threadIdx.x;
  int i = g >> 10, j = g & 1023;
  if (j < i) return;
  float v = C[g] - cs[i]*cs[j]*(1.0f/16384.0f);
  C[g] = v;
  C[j*1024 + i] = v;
  if (i == j) atomicAdd(tr, v);
}

__global__ void scal_k(const float* __restrict__ tr, float* __restrict__ scal){
  float trD = tr[0] * (1.0f/1024.0f);
  float c = 1.40f * trD, a = 0.25f * trD;
  scal[0] = 0.5f*(c + a);       // mid
  scal[1] = 2.0f/(c - a);       // 1/e
}

__global__ __launch_bounds__(256) void formChat_k(float* __restrict__ C, const float* __restrict__ scal){
  int g = blockIdx.x*256 + threadIdx.x;
  int i = g >> 10, j = g & 1023;
  float mid = scal[0], ie = scal[1];
  C[g] = ie*(C[g] - ((i==j) ? mid : 0.f));
}

__global__ __launch_bounds__(256) void formM_k(float* __restrict__ M){
  int g = blockIdx.x*256 + threadIdx.x;
  int i = g >> 10, j = g & 1023;
  if (j < i) return;
  float v = 2.f*M[g] - ((i==j) ? 1.f : 0.f);
  M[g] = v;
  M[j*1024 + i] = v;
}

__global__ void rng_k(float* __restrict__ Y){
  int idx = blockIdx.x*256 + threadIdx.x;   // 65536
  unsigned h = (unsigned)idx * 2654435761u;
  h ^= h >> 16; h *= 2246822519u; h ^= h >> 13; h *= 3266489917u; h ^= h >> 16;
  Y[idx] = (float)(h & 0xFFFFFFu) * (2.0f/16777216.0f) - 1.0f;
}

// partial[ks] = Yt * Cm  for k-chunk ks (M=64, N=64 tile, K=64 chunk). grid 256.
__global__ __launch_bounds__(256) void mv_k(const float* __restrict__ Yt, const float* __restrict__ Cm, float* __restrict__ P){
  int bx = blockIdx.x;
  int nt = bx & 15, ks = bx >> 4;
  int n0 = nt*64, k0 = ks*64;
  __shared__ __attribute__((aligned(16))) float At[64][68];
  __shared__ __attribute__((aligned(16))) float Bt[64][68];
  int t = threadIdx.x;
  #pragma unroll
  for (int w=0; w<4; ++w){
    int job = t + 256*w;
    int m  = job >> 4, f4 = job & 15;
    float4 v = *(const float4*)(Yt + (size_t)m*1024 + k0 + f4*4);
    At[f4*4+0][m] = v.x; At[f4*4+1][m] = v.y; At[f4*4+2][m] = v.z; At[f4*4+3][m] = v.w;
    int kk = job >> 4, fn = job & 15;
    *(float4*)&Bt[kk][fn*4] = *(const float4*)(Cm + (size_t)(k0+kk)*1024 + n0 + fn*4);
  }
  __syncthreads();
  int tm = t & 15, tn = t >> 4;
  float acc[4][4];
  #pragma unroll
  for (int i=0;i<4;++i)
    #pragma unroll
    for (int j=0;j<4;++j) acc[i][j]=0.f;
  for (int kk=0; kk<64; ++kk){
    float4 a = *(const float4*)&At[kk][tm*4];
    float4 b = *(const float4*)&Bt[kk][tn*4];
    float av[4] = {a.x,a.y,a.z,a.w};
    float bv[4] = {b.x,b.y,b.z,b.w};
    #pragma unroll
    for (int i=0;i<4;++i)
      #pragma unroll
      for (int j=0;j<4;++j) acc[i][j] += av[i]*bv[j];
  }
  #pragma unroll
  for (int i=0;i<4;++i){
    float4 o; o.x=acc[i][0]; o.y=acc[i][1]; o.z=acc[i][2]; o.w=acc[i][3];
    *(float4*)(P + (size_t)(ks*64 + tm*4 + i)*1024 + n0 + tn*4) = o;
  }
}

// combine 16 partials. mode 0: out = S (plain). mode 1: out = 2*S - Tk1 (Cheb recurrence in M).
__global__ __launch_bounds__(256) void combine_k(const float* __restrict__ P, const float* __restrict__ Tk1,
                                                 float* __restrict__ out, int mode){
  int idx = (blockIdx.x*256 + threadIdx.x)*4;
  float s0=0.f,s1=0.f,s2=0.f,s3=0.f;
  #pragma unroll
  for (int ks=0; ks<16; ++ks){
    const float4 p = *(const float4*)(P + (size_t)ks*65536 + idx);
    s0 += p.x; s1 += p.y; s2 += p.z; s3 += p.w;
  }
  float4 o;
  if (mode == 0){
    o.x=s0; o.y=s1; o.z=s2; o.w=s3;
  } else {
    const float4 t1 = *(const float4*)(Tk1 + idx);
    o.x = 2.f*s0 - t1.x; o.y = 2.f*s1 - t1.y;
    o.z = 2.f*s2 - t1.z; o.w = 2.f*s3 - t1.w;
  }
  *(float4*)(out+idx) = o;
}

// S[i][j] = sum_k A[i][k]*B[j][k]  (fp64 accumulate). grid 256: i = bx>>2, jg = bx&3.
__global__ __launch_bounds__(256) void gram_k(const float* __restrict__ A, const float* __restrict__ Bm, double* __restrict__ S){
  int bx = blockIdx.x;
  int i = bx >> 2, jg = bx & 3;
  __shared__ __attribute__((aligned(16))) float Ai[1024];
  __shared__ double red[16][17];
  int t = threadIdx.x;
  ((float4*)Ai)[t] = ((const float4*)(A + (size_t)i*1024))[t];
  __syncthreads();
  int jl = t >> 4, kp = t & 15;
  const float* Br = Bm + (size_t)(jg*16 + jl)*1024 + kp*64;
  const float* Ar = Ai + kp*64;
  double acc = 0.0;
  #pragma unroll 8
  for (int kk=0; kk<64; ++kk) acc += (double)Br[kk] * (double)Ar[kk];
  red[jl][kp] = acc;
  __syncthreads();
  if (t < 16){
    double s = 0.0;
    #pragma unroll
    for (int p2=0; p2<16; ++p2) s += red[t][p2];
    S[i*64 + jg*16 + t] = s;
  }
}

// fp64 Cholesky of 64x64, single wave, FIXED-TRIP masked rank-1 updates.
// col[j]=0 for j<=k kills below-range columns; j>t touches upper triangle (never read).
__global__ __launch_bounds__(64) void chol_k(const double* __restrict__ S, float* __restrict__ Lf){
  __shared__ double L[64][65];
  __shared__ double col[64];
  int t = threadIdx.x;
  for (int e=t; e<4096; e+=64) L[e>>6][e&63] = S[e];
  __syncthreads();
  for (int k=0; k<64; ++k){
    double lkk = sqrt(fmax(L[k][k], 1e-280));   // broadcast read
    double r = 1.0/lkk;
    double ck = (t > k) ? L[t][k]*r : 0.0;
    col[t] = ck;
    if (t == k) L[k][k] = lkk;
    if (t > k)  L[t][k] = ck;
    __syncthreads();
    #pragma unroll
    for (int j=0; j<64; j+=8){
      L[t][j+0] -= ck*col[j+0];
      L[t][j+1] -= ck*col[j+1];
      L[t][j+2] -= ck*col[j+2];
      L[t][j+3] -= ck*col[j+3];
      L[t][j+4] -= ck*col[j+4];
      L[t][j+5] -= ck*col[j+5];
      L[t][j+6] -= ck*col[j+6];
      L[t][j+7] -= ck*col[j+7];
    }
    __syncthreads();
  }
  for (int e=t; e<4096; e+=64){
    int i = e >> 6, j = e & 63;
    Lf[e] = (j < i) ? (float)L[i][j] : ((j == i) ? (float)(1.0/L[i][i]) : 0.f);
  }
}

// Qt = L^{-1} Yt by forward substitution per column k (1024 threads over 4 blocks)
__global__ __launch_bounds__(256) void applysolve_k(const float* __restrict__ Yin, const float* __restrict__ Lf, float* __restrict__ Qout){
  int k = blockIdx.x*256 + threadIdx.x;
  float z[64];
  #pragma unroll
  for (int c=0; c<64; ++c){
    float v = Yin[(size_t)c*1024 + k];
    #pragma unroll
    for (int j=0; j<c; ++j) v -= Lf[c*64+j]*z[j];
    z[c] = v * Lf[c*64+c];   // diag stores reciprocal
  }
  #pragma unroll
  for (int c=0; c<64; ++c) Qout[(size_t)c*1024 + k] = z[c];
}

// ---------- single-wave 64x64 symmetric top-16 eigensolver ----------
__device__ __forceinline__ double wsumd(double v){
  #pragma unroll
  for (int off=32; off; off>>=1) v += __shfl_xor(v, off, 64);
  return v;
}
__device__ __forceinline__ float wsumf(float v){
  #pragma unroll
  for (int off=32; off; off>>=1) v += __shfl_xor(v, off, 64);
  return v;
}
__device__ __forceinline__ double wmind(double v){
  #pragma unroll
  for (int off=32; off; off>>=1) v = fmin(v, __shfl_xor(v, off, 64));
  return v;
}
__device__ __forceinline__ double wmaxd(double v){
  #pragma unroll
  for (int off=32; off; off>>=1) v = fmax(v, __shfl_xor(v, off, 64));
  return v;
}

__global__ __launch_bounds__(64) void eig16_k(const double* __restrict__ Tin, float* __restrict__ V16){
  __shared__ double A[64][65];
  __shared__ double vbuf[64], qbuf[64];
  __shared__ double dd[64], ee[64], kap[64];
  __shared__ float dF[64], eF[64], e2F[64];
  __shared__ float lamF[16];
  __shared__ float IV[5][64][16];
  __shared__ float W[16][68];
  __shared__ float vb32[64];
  int t = threadIdx.x;               // single wave

  for (int e=t; e<4096; e+=64){
    int i = e >> 6, j = e & 63;
    A[i][j] = 0.5*(Tin[i*64+j] + Tin[j*64+i]);
  }
  __syncthreads();

  for (int k=0; k<62; ++k){
    double xi = (t > k) ? A[t][k] : 0.0;
    double sigma = wsumd(xi*xi);
    double x1 = A[k+1][k];
    if (sigma > 1e-200){
      double r = sqrt(sigma);
      double alpha = (x1 >= 0.0) ? -r : r;
      double kappa = sigma - alpha*x1;
      double vk = xi;
      if (t == k+1) vk = x1 - alpha;
      vbuf[t] = (t > k) ? vk : 0.0;
      if (t > k) A[t][k] = vk;
      if (t == 0){ ee[k] = alpha; kap[k] = kappa; }
      __syncthreads();
      int j0 = (k+1) & ~7;
      double p0=0.0,p1=0.0,p2=0.0,p3=0.0;
      for (int j=j0; j<64; j+=8){
        p0 += A[t][j+0]*vbuf[j+0]; p1 += A[t][j+1]*vbuf[j+1];
        p2 += A[t][j+2]*vbuf[j+2]; p3 += A[t][j+3]*vbuf[j+3];
        p0 += A[t][j+4]*vbuf[j+4]; p1 += A[t][j+5]*vbuf[j+5];
        p2 += A[t][j+6]*vbuf[j+6]; p3 += A[t][j+7]*vbuf[j+7];
      }
      double pi = (t > k) ? ((p0+p1)+(p2+p3))/kappa : 0.0;
      double vp = wsumd((t > k) ? vbuf[t]*pi : 0.0);
      double Kc = vp / (2.0*kappa);
      double qi = (t > k) ? (pi - Kc*vbuf[t]) : 0.0;
      qbuf[t] = qi;
      __syncthreads();
      double vi = (t > k) ? vbuf[t] : 0.0;
      for (int j=j0; j<64; j+=8){
        A[t][j+0] -= vi*qbuf[j+0] + qi*vbuf[j+0];
        A[t][j+1] -= vi*qbuf[j+1] + qi*vbuf[j+1];
        A[t][j+2] -= vi*qbuf[j+2] + qi*vbuf[j+2];
        A[t][j+3] -= vi*qbuf[j+3] + qi*vbuf[j+3];
        A[t][j+4] -= vi*qbuf[j+4] + qi*vbuf[j+4];
        A[t][j+5] -= vi*qbuf[j+5] + qi*vbuf[j+5];
        A[t][j+6] -= vi*qbuf[j+6] + qi*vbuf[j+6];
        A[t][j+7] -= vi*qbuf[j+7] + qi*vbuf[j+7];
      }
      __syncthreads();
    } else {
      if (t == 0){ ee[k] = 0.0; kap[k] = 0.0; }
      __syncthreads();
    }
  }
  dd[t] = A[t][t];
  if (t == 0){ ee[62] = A[63][62]; ee[63] = 0.0; kap[62] = 0.0; kap[63] = 0.0; }
  __syncthreads();
  dF[t] = (float)dd[t];
  eF[t] = (float)ee[t];
  e2F[t] = (float)(ee[t]*ee[t]);
  __syncthreads();

  double em1 = (t > 0) ? fabs(ee[t-1]) : 0.0;
  double ep  = fabs(ee[t]);
  double glo = wmind(dd[t] - em1 - ep);
  double ghi = wmaxd(dd[t] + em1 + ep);
  double span = ghi - glo + 1.0;
  float lo = (float)(glo - 0.001*span), hi = (float)(ghi + 0.001*span);

  int m = 48 + (t & 15);
  const float PIV = 1e-10f;
  for (int it=0; it<30; ++it){
    float x = 0.5f*(lo + hi);
    float q = dF[0] - x;
    int c = (q < 0.f) ? 1 : 0;
    #pragma unroll 1
    for (int j=1; j<64; ++j){
      float qs = (fabsf(q) < PIV) ? ((q < 0.f) ? -PIV : PIV) : q;
      q = dF[j] - x - e2F[j-1]/qs;
      c += (q < 0.f) ? 1 : 0;
    }
    if (c <= m) lo = x; else hi = x;
  }
  if (t < 16) lamF[t] = 0.5f*(lo + hi);
  __syncthreads();

  #define DLa(i) IV[0][i][t]
  #define DDa(i) IV[1][i][t]
  #define DUa(i) IV[2][i][t]
  #define DU2a(i) IV[3][i][t]
  #define Bv(i)  IV[4][i][t]
  if (t < 16){
    float lam = lamF[t];
    const float PIVF = 1e-6f;
    for (int i=0; i<64; ++i){
      DDa(i) = dF[i] - lam;
      DU2a(i) = 0.f;
      if (i < 63){ DUa(i) = eF[i]; DLa(i) = eF[i]; }
      unsigned hsh = (unsigned)(i*131 + t*1009 + 7);
      hsh ^= hsh >> 13; hsh *= 2654435761u; hsh ^= hsh >> 16;
      Bv(i) = (float)(hsh & 0xFFFF) * (1.5f/65536.0f) + 0.25f;
    }
    unsigned long long piv = 0ull;
    for (int i=0; i<63; ++i){
      float di = DDa(i), dli = DLa(i);
      if (fabsf(di) >= fabsf(dli)){
        if (fabsf(di) < PIVF) di = (di < 0.f) ? -PIVF : PIVF;
        float f = dli/di;
        DDa(i) = di; DLa(i) = f;
        DDa(i+1) -= f*DUa(i);
      } else {
        float f = di/dli;
        DDa(i) = dli; DLa(i) = f;
        float tmp = DUa(i);
        DUa(i) = DDa(i+1);
        DDa(i+1) = tmp - f*DDa(i+1);
        if (i < 62){ DU2a(i) = DUa(i+1); DUa(i+1) = -f*DUa(i+1); }
        piv |= (1ull << i);
      }
    }
    #pragma unroll 1
    for (int iter=0; iter<2; ++iter){
      for (int i=0; i<63; ++i){
        if (!((piv >> i) & 1ull)){
          Bv(i+1) -= DLa(i)*Bv(i);
        } else {
          float tm = Bv(i);
          Bv(i) = Bv(i+1);
          Bv(i+1) = tm - DLa(i)*Bv(i);
        }
      }
      float p63 = DDa(63); if (fabsf(p63) < PIVF) p63 = (p63 < 0.f) ? -PIVF : PIVF;
      Bv(63) = Bv(63)/p63;
      float p62 = DDa(62); if (fabsf(p62) < PIVF) p62 = (p62 < 0.f) ? -PIVF : PIVF;
      Bv(62) = (Bv(62) - DUa(62)*Bv(63))/p62;
      for (int i=61; i>=0; --i){
        float pi2 = DDa(i); if (fabsf(pi2) < PIVF) pi2 = (pi2 < 0.f) ? -PIVF : PIVF;
        Bv(i) = (Bv(i) - DUa(i)*Bv(i+1) - DU2a(i)*Bv(i+2))/pi2;
      }
      float ss = 0.f;
      for (int i=0; i<64; ++i){ float z = Bv(i); ss += z*z; }
      float rn = rsqrtf(fmaxf(ss, 1e-30f));
      for (int i=0; i<64; ++i) Bv(i) *= rn;
    }
    for (int i=0; i<64; ++i) W[t][i] = Bv(i);
  }
  __syncthreads();

  for (int c=0; c<16; ++c){
    float wi = W[c][t];
    float s2 = wsumf(wi*wi);
    float rn = rsqrtf(fmaxf(s2, 1e-30f));
    wi *= rn;
    W[c][t] = wi;
    for (int c2=c+1; c2<16; ++c2){
      float d2 = wsumf(wi * W[c2][t]);
      W[c2][t] -= d2*wi;
    }
    __syncthreads();
  }

  int cc = t >> 2, part = t & 3;
  for (int k=61; k>=0; --k){
    double kpd = kap[k];
    if (kpd == 0.0) continue;
    float invk = (float)(1.0/kpd);
    vb32[t] = (t > k) ? (float)A[t][k] : 0.f;
    __syncthreads();
    float ps = 0.f;
    #pragma unroll
    for (int mm=0; mm<16; ++mm){
      int i = part*16 + mm;
      ps += vb32[i]*W[cc][i];
    }
    ps += __shfl_xor(ps, 1, 64);
    ps += __shfl_xor(ps, 2, 64);
    float sc = ps * invk;
    #pragma unroll
    for (int mm=0; mm<16; ++mm){
      int i = part*16 + mm;
      W[cc][i] -= vb32[i]*sc;
    }
    __syncthreads();
  }

  for (int e=t; e<1024; e+=64){
    int j = e >> 4, c = e & 15;
    V16[e] = W[c][j];
  }
}
#undef DLa
#undef DDa
#undef DUa
#undef DU2a
#undef Bv

__global__ __launch_bounds__(256) void buildUt_k(const float* __restrict__ V16,
                                                 const float* __restrict__ Qt, float* __restrict__ Ut, float* __restrict__ UtT){
  int bx = blockIdx.x;
  int c = bx & 15, kc = bx >> 4;
  int k = kc*256 + threadIdx.x;
  float acc = 0.f;
  #pragma unroll
  for (int j=0; j<64; ++j) acc += V16[j*16 + c] * Qt[(size_t)j*1024 + k];
  Ut[(size_t)c*1024 + k] = acc;
  UtT[(size_t)k*16 + c] = acc;
}

__global__ void s16_k(const float* __restrict__ cs, const float* __restrict__ Ut, float* __restrict__ s16){
  __shared__ float red[16][17];
  int t = threadIdx.x;
  int c = t & 15, part = t >> 4;
  float acc = 0.f;
  for (int d=0; d<64; ++d) acc += cs[part*64 + d] * Ut[(size_t)c*1024 + part*64 + d];
  red[c][part] = acc;
  __syncthreads();
  if (t < 16){
    float s = 0.f;
    #pragma unroll
    for (int p2=0; p2<16; ++p2) s += red[t][p2];
    s16[t] = s * (1.0f/16384.0f);
  }
}

__global__ __launch_bounds__(256) void proj_k(const float* __restrict__ X, const float* __restrict__ UtT,
                                              const float* __restrict__ s16, float* __restrict__ F){
  int r0 = blockIdx.x * 64;
  int t = threadIdx.x;
  __shared__ __attribute__((aligned(16))) float uts[16384];   // [1024][16]
  #pragma unroll
  for (int w=0; w<16; ++w)
    ((float4*)uts)[t + 256*w] = ((const float4*)UtT)[t + 256*w];
  __syncthreads();
  int row = t & 63, kp = t >> 6;
  const float* xr = X + (size_t)(r0 + row)*1024 + kp*256;
  const float* ut = uts + kp*256*16;
  float acc[16];
  #pragma unroll
  for (int c=0;c<16;++c) acc[c] = 0.f;
  for (int dd=0; dd<256; dd+=4){
    float4 xv4 = *(const float4*)(xr + dd);
    float xv[4] = {xv4.x, xv4.y, xv4.z, xv4.w};
    #pragma unroll
    for (int u=0; u<4; ++u)
      #pragma unroll
      for (int c=0;c<16;++c) acc[c] += xv[u] * ut[(dd+u)*16 + c];
  }
  __shared__ float part[4][64][16];
  #pragma unroll
  for (int c=0;c<16;++c) part[kp][row][c] = acc[c];
  __syncthreads();
  int cq = t >> 6;
  #pragma unroll
  for (int ccx=0; ccx<4; ++ccx){
    int c = cq*4 + ccx;
    float v = part[0][row][c] + part[1][row][c] + part[2][row][c] + part[3][row][c] - s16[c];
    F[(size_t)(r0 + row)*16 + c] = v;
  }
}

__global__ __launch_bounds__(256) void stats_k(const float* __restrict__ F, const int* __restrict__ lbl, float* __restrict__ SG){
  __shared__ float st[10][154];
  int t = threadIdx.x;
  for (int e=t; e<1540; e+=256) st[e/154][e%154] = 0.f;
  __syncthreads();
  int r = blockIdx.x*256 + t;
  float f[16];
  #pragma unroll
  for (int w=0; w<4; ++w){
    float4 v = *(const float4*)(F + (size_t)r*16 + w*4);
    f[w*4+0]=v.x; f[w*4+1]=v.y; f[w*4+2]=v.z; f[w*4+3]=v.w;
  }
  int c = lbl[r];
  if ((unsigned)c < 10u){
    float* bs = &st[c][0];
    atomicAdd(&bs[0], 1.f);
    #pragma unroll
    for (int a=0;a<16;++a) atomicAdd(&bs[1+a], f[a]);
    int sidx = 17;
    #pragma unroll
    for (int a=0;a<16;++a)
      #pragma unroll
      for (int b2=a;b2<16;++b2) atomicAdd(&bs[sidx++], f[a]*f[b2]);
  }
  __syncthreads();
  for (int e=t; e<1530; e+=256) atomicAdd(&SG[e], st[e/153][e%153]);
}

__global__ __launch_bounds__(256) void final_k(const float* __restrict__ SG, float* __restrict__ out){
  __shared__ double cnt[10], safe[10], ldet[10];
  __shared__ double mean[10][16];
  __shared__ double Sig[10][16][16];
  __shared__ double Inv[10][16][16];
  __shared__ double red[128];
  int t = threadIdx.x;
  if (t < 10){
    double c0 = (double)SG[t*153];
    cnt[t] = c0; safe[t] = (c0 > 0.0) ? c0 : 1.0;
  }
  __syncthreads();
  for (int e=t; e<160; e+=256){
    int c = e >> 4, a = e & 15;
    mean[c][a] = (double)SG[c*153 + 1 + a] / safe[c];
  }
  __syncthreads();
  for (int e=t; e<2560; e+=256){
    int c = e >> 8, ab = e & 255, a = ab >> 4, b2 = ab & 15;
    int lo = a < b2 ? a : b2, hi = a < b2 ? b2 : a;
    int ti = lo*(33 - lo)/2 + (hi - lo);
    Sig[c][a][b2] = (double)SG[c*153 + 17 + ti]/safe[c] - mean[c][a]*mean[c][b2] + ((a==b2)?1.0:0.0);
  }
  __syncthreads();
  if (t < 10){
    for (int a=0;a<16;++a)
      for (int b2=0;b2<16;++b2) Inv[t][a][b2] = Sig[t][a][b2];
    double ld2 = 0.0;
    for (int k=0;k<16;++k){
      double v = Inv[t][k][k];
      for (int j=0;j<k;++j) v -= Inv[t][k][j]*Inv[t][k][j];
      v = fmax(v, 1e-280);
      double lkk = sqrt(v);
      Inv[t][k][k] = lkk; ld2 += log(lkk);
      for (int i=k+1;i<16;++i){
        double w = Inv[t][i][k];
        for (int j=0;j<k;++j) w -= Inv[t][i][j]*Inv[t][k][j];
        Inv[t][i][k] = w / lkk;
      }
    }
    ldet[t] = 2.0*ld2;
    for (int j=0;j<16;++j){
      double dj = 1.0 / Inv[t][j][j];
      Inv[t][j][j] = dj;
      for (int i=j+1;i<16;++i){
        double ssum = Inv[t][i][j]*dj;
        for (int k=j+1;k<i;++k) ssum += Inv[t][i][k]*Inv[t][k][j];
        Inv[t][i][j] = -ssum / Inv[t][i][i];
      }
    }
    double dg[16];
    #pragma unroll
    for (int a=0;a<16;++a){
      double s2 = 0.0;
      for (int k=a;k<16;++k){ double x = Inv[t][k][a]; s2 += x*x; }
      dg[a] = s2;
    }
    for (int a=0;a<16;++a)
      for (int b2=a+1;b2<16;++b2){
        double s2 = 0.0;
        for (int k=b2;k<16;++k) s2 += Inv[t][k][a]*Inv[t][k][b2];
        Inv[t][a][b2] = s2;
      }
    for (int a=0;a<16;++a) Inv[t][a][a] = dg[a];
    for (int a=0;a<16;++a)
      for (int b2=a+1;b2<16;++b2) Inv[t][b2][a] = Inv[t][a][b2];
  }
  __syncthreads();
  double contrib = 0.0;
  if (t < 100){
    int i = t/10, j = t%10;
    if (i != j && cnt[i] > 0.0 && cnt[j] > 0.0){
      double tr = 0.0;
      for (int a=0;a<16;++a)
        for (int b2=0;b2<16;++b2) tr += Inv[j][a][b2]*Sig[i][b2][a];
      double dm[16];
      #pragma unroll
      for (int a=0;a<16;++a) dm[a] = mean[j][a] - mean[i][a];
      double mah = 0.0;
      for (int a=0;a<16;++a){
        double rs = 0.0;
        for (int b2=0;b2<16;++b2) rs += Inv[j][a][b2]*dm[b2];
        mah += dm[a]*rs;
      }
      double kl = 0.5*(tr + mah - 16.0 + ldet[j] - ldet[i]);
      contrib = kl * cnt[i]*cnt[j];
    }
  }
  if (t < 128) red[t] = contrib;
  __syncthreads();
  for (int off=64; off>0; off >>= 1){
    if (t < off) red[t] += red[t+off];
    __syncthreads();
  }
  if (t == 0) out[0] = (float)(red[0] / (16384.0*16384.0*16384.0));
}

// ---------------- host ----------------
extern "C" void kernel_launch(void* const* d_in, const int* in_sizes, int n_in,
                              void* d_out, int out_size, void* d_ws, size_t ws_size,
                              hipStream_t stream){
  (void)in_sizes; (void)n_in; (void)out_size; (void)ws_size;
  const float* X  = (const float*)d_in[0];
  const int* lbl  = (const int*)d_in[1];
  char* ws = (char*)d_ws;
  float*  C    = (float*)(ws + OFF_C);
  float*  Mm   = (float*)(ws + OFF_M);
  float*  P    = (float*)(ws + OFF_P);
  float*  Y0   = (float*)(ws + OFF_Y0);
  float*  Y1   = (float*)(ws + OFF_Y1);
  float*  Y2   = (float*)(ws + OFF_Y2);
  float*  Y3   = (float*)(ws + OFF_Y3);
  float*  CQ   = (float*)(ws + OFF_CQ);
  double* S64  = (double*)(ws + OFF_S64);
  float*  LF   = (float*)(ws + OFF_LF);
  double* T64  = (double*)(ws + OFF_T64);
  float*  V16  = (float*)(ws + OFF_V16);
  float*  UT   = (float*)(ws + OFF_UT);
  float*  UTT  = (float*)(ws + OFF_UTT);
  float*  S16  = (float*)(ws + OFF_S16);
  float*  CS   = (float*)(ws + OFF_CS);
  float*  TRC  = (float*)(ws + OFF_TR);
  float*  SCAL = (float*)(ws + OFF_SCAL);
  float*  STAT = (float*)(ws + OFF_STAT);
  float*  F    = (float*)(ws + OFF_F);
  float*  OUT  = (float*)d_out;

  hipMemsetAsync(C, 0, 4*1024*1024, stream);
  hipMemsetAsync(Mm, 0, 4*1024*1024, stream);
  hipMemsetAsync(ws + OFF_CS, 0, 12800, stream);   // CS + TR + SCAL + STAT

  colsum_k<<<64, 256, 0, stream>>>(X, CS);
  syrk_k<<<36*24, 256, 0, stream>>>(X, C);
  formC_k<<<4096, 256, 0, stream>>>(C, CS, TRC);
  scal_k<<<1, 1, 0, stream>>>(TRC, SCAL);
  formChat_k<<<4096, 256, 0, stream>>>(C, SCAL);       // C := Chat (in place)
  syrkM_k<<<36*8, 256, 0, stream>>>(C, Mm);            // Macc = Chat^2 (upper)
  formM_k<<<4096, 256, 0, stream>>>(Mm);               // M = 2*Macc - I, mirrored
  rng_k<<<256, 256, 0, stream>>>(Y0);

  // Chebyshev stage in M: U_{s+1} = 2 M U_s - U_{s-1} (T_10(M) == T_20(Chat))
  auto cheb = [&](float* in, float* z0, float* z1, float* z2) -> float* {
    float* bufs[3] = {z0, z1, z2};
    float* prev = in;
    float* cur = in;
    for (int s=0; s<CHEB_D; ++s){
      float* dst = bufs[s % 3];
      mv_k<<<256, 256, 0, stream>>>(cur, Mm, P);
      combine_k<<<64, 256, 0, stream>>>(P, prev, dst, (s == 0) ? 0 : 1);
      prev = cur; cur = dst;
    }
    return cur;   // = z0 for CHEB_D=10
  };
  auto cholqr = [&](float* Yin, float* Qout){
    gram_k<<<256, 256, 0, stream>>>(Yin, Yin, S64);
    chol_k<<<1, 64, 0, stream>>>(S64, LF);
    applysolve_k<<<4, 256, 0, stream>>>(Yin, LF, Qout);
  };

  // stage 1: filter random block, single CholQR (conditioning only)
  cheb(Y0, Y1, Y2, Y3);                // -> Y1
  cholqr(Y1, Y2);                      // Q1 = Y2
  // stage 2 + CholQR2 (full orthonormality before RR)
  cheb(Y2, Y0, Y1, Y3);                // -> Y0
  cholqr(Y0, Y1);
  cholqr(Y1, Y2);                      // Qf = Y2

  // Rayleigh-Ritz in M-space: T = Q^T M Q (same top-16 invariant subspace as C)
  mv_k<<<256, 256, 0, stream>>>(Y2, Mm, P);
  combine_k<<<64, 256, 0, stream>>>(P, Y2, CQ, 0);     // CQ = Q M
  gram_k<<<256, 256, 0, stream>>>(Y2, CQ, T64);
  eig16_k<<<1, 64, 0, stream>>>(T64, V16);
  buildUt_k<<<64, 256, 0, stream>>>(V16, Y2, UT, UTT);

  // project and GMM loss
  s16_k<<<1, 256, 0, stream>>>(CS, UT, S16);
  proj_k<<<256, 256, 0, stream>>>(X, UTT, S16, F);
  stats_k<<<64, 256, 0, stream>>>(F, lbl, STAT);
  final_k<<<1, 256, 0, stream>>>(STAT, OUT);
}